// Round 18
// baseline (144.342 us; speedup 1.0000x reference)
//
#include <hip/hip_runtime.h>
#include <math.h>

#define D_MODEL 1024
#define NHEADS  16
#define HEADD   64
#define NFREQ   32
#define BATCH   2
#define CSEQ    2048
#define NROWS   (BATCH*CSEQ)   // 4096
#define NQKV    (3*D_MODEL)    // 3072

typedef _Float16 half8  __attribute__((ext_vector_type(8)));
typedef _Float16 half4v __attribute__((ext_vector_type(4)));
typedef float    f32x4  __attribute__((ext_vector_type(4)));

// async global->LDS, 16B per lane. dest is WAVE-UNIFORM base (HW adds lane*16).
__device__ __forceinline__ void async16(void* lds, const void* g)
{
    __builtin_amdgcn_global_load_lds((const __attribute__((address_space(1))) unsigned int*)g,
                                     (__attribute__((address_space(3))) unsigned int*)lds,
                                     16, 0, 0);
}

// ---------------------------------------------------------------------------
// Fused small prep: blocks 0..255 -> cos/sin table; blocks 256..267 -> bias_eff
// ---------------------------------------------------------------------------
__global__ __launch_bounds__(256) void prep_misc_kernel(
    float2* __restrict__ cs,
    const float* __restrict__ bq, const float* __restrict__ bkv, float* __restrict__ be)
{
    int bid = blockIdx.x;
    int tid = threadIdx.x;
    if (bid < 256) {
        int i = bid * 256 + tid;
        int c = i >> 5, f = i & (NFREQ - 1);
        double mel_max = 2595.0 * log10(21.0);
        double step    = mel_max / (double)(NFREQ - 1);
        double freq    = 200.0 * (pow(10.0, step * (double)f / 2595.0) - 1.0) / 1000.0;
        float fr = (float)freq;
        float th = (float)c * fr;
        float s, co;
        sincosf(th, &s, &co);
        cs[i] = make_float2(co, s);
    } else {
        int i = (bid - 256) * 256 + tid;
        if (i < D_MODEL) be[i] = bq[i];
        else if (i < NQKV) be[i] = bkv[i - D_MODEL];
    }
}

// ---------------------------------------------------------------------------
// All weight transposes in one launch. Transpose + optional LN-gain row-scale
// + cast fp32(R x C)->fp16(C x R); optional LN-bias fold via atomicAdd.
// blocks: [0,1024) Wq ; [1024,3072) Wkv ; [3072,4096) Wout
// ---------------------------------------------------------------------------
__global__ void transpose_all_kernel(
    const float* __restrict__ Wq,  const float* __restrict__ Wkv,
    const float* __restrict__ Wout,
    const float* __restrict__ gq,  const float* __restrict__ bqf,
    const float* __restrict__ gkv, const float* __restrict__ bkvf,
    _Float16* __restrict__ WqkvT, _Float16* __restrict__ WoutT,
    float* __restrict__ bias_acc)
{
    const float* in; _Float16* out; int R, C, rowoff;
    const float* scale; const float* bfold;
    int id = blockIdx.x, bx, by;
    if (id < 1024) {
        in = Wq; out = WqkvT; R = D_MODEL; C = D_MODEL; rowoff = 0;
        scale = gq; bfold = bqf;
        bx = (id & 31) * 32; by = (id >> 5) * 32;
    } else if (id < 3072) {
        int t = id - 1024;
        in = Wkv; out = WqkvT; R = D_MODEL; C = 2 * D_MODEL; rowoff = D_MODEL;
        scale = gkv; bfold = bkvf;
        bx = (t & 63) * 32; by = (t >> 6) * 32;
    } else {
        int t = id - 3072;
        in = Wout; out = WoutT; R = D_MODEL; C = D_MODEL; rowoff = 0;
        scale = nullptr; bfold = nullptr;
        bx = (t & 31) * 32; by = (t >> 5) * 32;
    }

    __shared__ float tb[32][33];
    __shared__ float part[4][32];
    int tx = threadIdx.x, ty = threadIdx.y;
    #pragma unroll
    for (int i = ty; i < 32; i += 8)
        tb[i][tx] = in[(size_t)(by + i) * C + bx + tx];
    __syncthreads();
    float sc = scale ? scale[by + tx] : 1.f;
    #pragma unroll
    for (int i = ty; i < 32; i += 8)
        out[(size_t)(rowoff + bx + i) * R + by + tx] = (_Float16)(tb[tx][i] * sc);
    if (bfold) {
        float p = 0.f;
        #pragma unroll
        for (int i = ty; i < 32; i += 8)
            p += bfold[by + i] * tb[i][tx];
        p += __shfl_xor(p, 32);
        if ((ty & 1) == 0) part[ty >> 1][tx] = p;
        __syncthreads();
        if (ty == 0)
            atomicAdd(&bias_acc[rowoff + bx + tx],
                      part[0][tx] + part[1][tx] + part[2][tx] + part[3][tx]);
    }
}

// ---------------------------------------------------------------------------
// LN stats + radius; writes xn fp16 (normalized; gains folded into weights)
// ---------------------------------------------------------------------------
__global__ __launch_bounds__(256) void ln_radius_kernel(
    const float* __restrict__ x,
    const float* __restrict__ Wr,  const float* __restrict__ br,
    _Float16* __restrict__ xn, float* __restrict__ radius)
{
    int row = blockIdx.x;
    int tid = threadIdx.x;
    float4 xv = ((const float4*)(x + (size_t)row * D_MODEL))[tid];
    float4 wv = ((const float4*)Wr)[tid];
    float s  = xv.x + xv.y + xv.z + xv.w;
    float ss = xv.x*xv.x + xv.y*xv.y + xv.z*xv.z + xv.w*xv.w;
    float dr = xv.x*wv.x + xv.y*wv.y + xv.z*wv.z + xv.w*wv.w;
    #pragma unroll
    for (int off = 1; off < 64; off <<= 1) {
        s  += __shfl_xor(s, off);
        ss += __shfl_xor(ss, off);
        dr += __shfl_xor(dr, off);
    }
    __shared__ float red[3][4];
    int w = tid >> 6, lane = tid & 63;
    if (lane == 0) { red[0][w] = s; red[1][w] = ss; red[2][w] = dr; }
    __syncthreads();
    s  = red[0][0] + red[0][1] + red[0][2] + red[0][3];
    ss = red[1][0] + red[1][1] + red[1][2] + red[1][3];
    float mean = s * (1.f / D_MODEL);
    float var  = ss * (1.f / D_MODEL) - mean * mean;
    float rinv = rsqrtf(var + 1e-5f);
    half4v o4 = { (_Float16)((xv.x - mean) * rinv), (_Float16)((xv.y - mean) * rinv),
                  (_Float16)((xv.z - mean) * rinv), (_Float16)((xv.w - mean) * rinv) };
    *(half4v*)&xn[(size_t)row * D_MODEL + tid * 4] = o4;
    if (tid == 0) {
        float drt = red[2][0] + red[2][1] + red[2][2] + red[2][3];
        float p = (drt + br[0]) * 0.01f;
        radius[row] = fminf(fmaxf(p, 0.5f), 2.0f);
    }
}

// ---------------------------------------------------------------------------
// Pipelined GEMM core (128x128): BK=32, THREE LDS buffers, counted
// s_waitcnt vmcnt(4) + raw s_barrier; stage(t+1) loads stay in flight.
// ---------------------------------------------------------------------------
__device__ __forceinline__ void gemm_core32p(
    const _Float16* __restrict__ A, const _Float16* __restrict__ B,
    int bm, int bn, int K, _Float16* As, _Float16* Bs, f32x4 (*acc)[4])
{
    int tid = threadIdx.x, lane = tid & 63, w = tid >> 6;
    int wm = w >> 1, wn = w & 1;
    int l15 = lane & 15, lg = lane >> 4;
    int sr  = lane >> 2;
    int sch = lane & 3;

    auto stage = [&](int buf, int k0) {
        #pragma unroll
        for (int i = 0; i < 2; ++i) {
            int seg = w * 2 + i;
            int row = seg * 16 + sr;
            async16(&As[buf * 4096 + seg * 512], &A[(size_t)(bm + row) * K + k0 + sch * 8]);
            async16(&Bs[buf * 4096 + seg * 512], &B[(size_t)(bn + row) * K + k0 + sch * 8]);
        }
    };

    int nt = K >> 5;
    stage(0, 0);
    stage(1, 32);

    for (int t = 0; t < nt; ++t) {
        if (t + 1 < nt) asm volatile("s_waitcnt vmcnt(4)" ::: "memory");
        else            asm volatile("s_waitcnt vmcnt(0)" ::: "memory");
        __builtin_amdgcn_sched_barrier(0);
        __builtin_amdgcn_s_barrier();
        __builtin_amdgcn_sched_barrier(0);
        if (t + 2 < nt) stage((t + 2) % 3, (t + 2) << 5);

        const _Float16* Ab = &As[(t % 3) * 4096];
        const _Float16* Bb = &Bs[(t % 3) * 4096];
        half8 af[4], bf[4];
        #pragma unroll
        for (int m = 0; m < 4; ++m)
            af[m] = *(const half8*)&Ab[(wm * 64 + m * 16 + l15) * 32 + lg * 8];
        #pragma unroll
        for (int n = 0; n < 4; ++n)
            bf[n] = *(const half8*)&Bb[(wn * 64 + n * 16 + l15) * 32 + lg * 8];
        #pragma unroll
        for (int m = 0; m < 4; ++m)
            #pragma unroll
            for (int n = 0; n < 4; ++n)
                acc[m][n] = __builtin_amdgcn_mfma_f32_16x16x32_f16(af[m], bf[n], acc[m][n], 0, 0, 0);
    }
}

// ---------------------------------------------------------------------------
// Fused qkv GEMM: xn (M=4096 x K=1024) x WqkvT (N=3072) + bias_eff.
// q/k epilogue: bias + RoPE + head-LN (q pre-scaled 0.125 = 1/sqrt(HD)).
// V epilogue: bias + DIRECT transposed store into vT (B,H,HD,C).
// ---------------------------------------------------------------------------
__global__ __launch_bounds__(256, 3) void gemm_qkv_kernel(
    const _Float16* __restrict__ xn,  const _Float16* __restrict__ WT,
    const float* __restrict__ bias_eff,
    const float* __restrict__ radius, const float2* __restrict__ cs_tab,
    const float* __restrict__ lnh_g,  const float* __restrict__ lnh_b,
    _Float16* __restrict__ qn, _Float16* __restrict__ kn, _Float16* __restrict__ vT)
{
    __shared__ _Float16 As[3 * 4096];
    __shared__ _Float16 Bs[3 * 4096];
    int orig = blockIdx.x;
    int wg = (orig & 7) * 96 + (orig >> 3);   // bijective, 768 = 8*96
    int bm = (wg / 24) * 128;
    int bn = (wg % 24) * 128;

    f32x4 acc[4][4];
    f32x4 z = {0.f, 0.f, 0.f, 0.f};
    #pragma unroll
    for (int m = 0; m < 4; ++m)
        #pragma unroll
        for (int n = 0; n < 4; ++n) acc[m][n] = z;

    gemm_core32p(xn, WT, bm, bn, D_MODEL, As, Bs, acc);

    int tid = threadIdx.x, lane = tid & 63, w = tid >> 6;
    int wm = w >> 1, wn = w & 1;
    int l15 = lane & 15, lg = lane >> 4;
    int colbase = bn + wn * 64;

    float bb4[4];
    #pragma unroll
    for (int n = 0; n < 4; ++n) bb4[n] = bias_eff[colbase + n * 16 + l15];

    if (colbase >= 2 * D_MODEL) {
        // ---- V epilogue: bias + direct transposed store to vT (B,H,HD,C) ----
        int vcolb = colbase - 2 * D_MODEL;
        int h = vcolb >> 6;
        #pragma unroll
        for (int m = 0; m < 4; ++m) {
            int row0 = bm + wm * 64 + m * 16 + lg * 4;
            int b = row0 >> 11, c = row0 & (CSEQ - 1);
            #pragma unroll
            for (int n = 0; n < 4; ++n) {
                int d = n * 16 + l15;
                half4v v4 = { (_Float16)(acc[m][n][0] + bb4[n]),
                              (_Float16)(acc[m][n][1] + bb4[n]),
                              (_Float16)(acc[m][n][2] + bb4[n]),
                              (_Float16)(acc[m][n][3] + bb4[n]) };
                *(half4v*)&vT[((size_t)(b * NHEADS + h) * HEADD + d) * CSEQ + c] = v4;
            }
        }
        return;
    }

    bool isq = colbase < D_MODEL;
    int h = (colbase & (D_MODEL - 1)) >> 6;
    _Float16* dst = isq ? qn : kn;
    float qs = isq ? 0.125f : 1.f;
    bool im = (l15 & 1) != 0;

    float g4[4], bh4[4];
    #pragma unroll
    for (int n = 0; n < 4; ++n) {
        g4[n]  = lnh_g[n * 16 + l15];
        bh4[n] = lnh_b[n * 16 + l15];
    }

    #pragma unroll
    for (int m = 0; m < 4; ++m)
        #pragma unroll
        for (int r = 0; r < 4; ++r) {
            int row = bm + wm * 64 + m * 16 + lg * 4 + r;
            int b = row >> 11, c = row & (CSEQ - 1);
            float rr = radius[row];
            float vals[4];
            float s = 0.f, ss = 0.f;
            #pragma unroll
            for (int n = 0; n < 4; ++n) {
                float v0 = acc[m][n][r] + bb4[n];
                float pr = __shfl_xor(v0, 1);
                float2 cs = cs_tab[c * NFREQ + ((n * 16 + l15) >> 1)];
                float xr_ = im ? pr : v0;
                float xi_ = im ? v0 : pr;
                float rot = im ? rr * (xr_ * cs.y + xi_ * cs.x)
                               : rr * (xr_ * cs.x - xi_ * cs.y);
                vals[n] = rot;
                s += rot; ss += rot * rot;
            }
            #pragma unroll
            for (int off = 1; off < 16; off <<= 1) {
                s  += __shfl_xor(s, off);
                ss += __shfl_xor(ss, off);
            }
            float mean = s * (1.f / 64.f);
            float var  = ss * (1.f / 64.f) - mean * mean;
            float ri   = rsqrtf(var + 1e-5f);
            size_t base = ((size_t)(b * NHEADS + h) * CSEQ + c) * HEADD;
            #pragma unroll
            for (int n = 0; n < 4; ++n) {
                float o = ((vals[n] - mean) * ri * g4[n] + bh4[n]) * qs;
                dst[base + n * 16 + l15] = (_Float16)o;
            }
        }
}

// ---------------------------------------------------------------------------
// Output GEMM: 128x64 tiles, grid 512 (2 blocks/CU), 3-buffer counted-vmcnt
// pipeline (3 loads/stage -> vmcnt(3)).
// ---------------------------------------------------------------------------
__global__ __launch_bounds__(256, 4) void gemm_out_kernel(
    const _Float16* __restrict__ A, const _Float16* __restrict__ BT,
    const float* __restrict__ bias, float* __restrict__ C)
{
    __shared__ _Float16 As[3 * 4096];
    __shared__ _Float16 Bs[3 * 2048];
    int orig = blockIdx.x;
    int wg = (orig & 7) * 64 + (orig >> 3);   // bijective, 512 = 8*64
    int bm = (wg >> 4) * 128;                 // 32 m-tiles
    int bn = (wg & 15) * 64;                  // 16 n-tiles

    int tid = threadIdx.x, lane = tid & 63, w = tid >> 6;
    int wm = w >> 1, wn = w & 1;
    int l15 = lane & 15, lg = lane >> 4;
    int sr  = lane >> 2;
    int sch = lane & 3;

    f32x4 acc[4][2];
    f32x4 z = {0.f, 0.f, 0.f, 0.f};
    #pragma unroll
    for (int m = 0; m < 4; ++m)
        #pragma unroll
        for (int n = 0; n < 2; ++n) acc[m][n] = z;

    auto stage = [&](int buf, int k0) {
        #pragma unroll
        for (int i = 0; i < 2; ++i) {
            int seg = w * 2 + i;
            int row = seg * 16 + sr;
            async16(&As[buf * 4096 + seg * 512], &A[(size_t)(bm + row) * D_MODEL + k0 + sch * 8]);
        }
        int brow = w * 16 + sr;
        async16(&Bs[buf * 2048 + w * 512], &BT[(size_t)(bn + brow) * D_MODEL + k0 + sch * 8]);
    };

    stage(0, 0);
    stage(1, 32);
    for (int t = 0; t < 32; ++t) {
        if (t + 1 < 32) asm volatile("s_waitcnt vmcnt(3)" ::: "memory");
        else            asm volatile("s_waitcnt vmcnt(0)" ::: "memory");
        __builtin_amdgcn_sched_barrier(0);
        __builtin_amdgcn_s_barrier();
        __builtin_amdgcn_sched_barrier(0);
        if (t + 2 < 32) stage((t + 2) % 3, (t + 2) << 5);

        const _Float16* Ab = &As[(t % 3) * 4096];
        const _Float16* Bb = &Bs[(t % 3) * 2048];
        half8 af[4], bf[2];
        #pragma unroll
        for (int m = 0; m < 4; ++m)
            af[m] = *(const half8*)&Ab[(wm * 64 + m * 16 + l15) * 32 + lg * 8];
        #pragma unroll
        for (int n = 0; n < 2; ++n)
            bf[n] = *(const half8*)&Bb[(wn * 32 + n * 16 + l15) * 32 + lg * 8];
        #pragma unroll
        for (int m = 0; m < 4; ++m)
            #pragma unroll
            for (int n = 0; n < 2; ++n)
                acc[m][n] = __builtin_amdgcn_mfma_f32_16x16x32_f16(af[m], bf[n], acc[m][n], 0, 0, 0);
    }

    #pragma unroll
    for (int m = 0; m < 4; ++m) {
        int row = bm + wm * 64 + m * 16 + lg * 4;
        #pragma unroll
        for (int n = 0; n < 2; ++n) {
            int col = bn + wn * 32 + n * 16 + l15;
            float bb = bias[col];
            #pragma unroll
            for (int r = 0; r < 4; ++r)
                C[(size_t)(row + r) * D_MODEL + col] = acc[m][n][r] + bb;
        }
    }
}

// ---------------------------------------------------------------------------
// Flash attention v12: R17 structure (8 waves x 16 q = 128 q/block, 512
// threads, grid 512, reg-P O^T PV, online defer-max, counted-vmcnt raw
// barriers) deepened to FOUR LDS buffers: 2 tiles (4 loads/wave) stay in
// flight across each barrier -- prefetch cover ~2x the L2/HBM latency.
// LDS 64KB, 2 blocks/CU x 8 waves = 16 waves/CU (unchanged).
// ---------------------------------------------------------------------------
#define KVB 64
#define NT  (CSEQ / KVB)

__global__ __launch_bounds__(512, 4) void attn_kernel(
    const _Float16* __restrict__ qn, const _Float16* __restrict__ kn,
    const _Float16* __restrict__ vT, _Float16* __restrict__ o)
{
    __shared__ _Float16 KsB[4][KVB * 64];   // 32 KB
    __shared__ _Float16 VsB[4][KVB * 64];   // 32 KB
    int tid = threadIdx.x, lane = tid & 63, w = tid >> 6;   // w = 0..7
    int l15 = lane & 15, lg = lane >> 4;

    int orig = blockIdx.x;
    int wg   = (orig & 7) * 64 + (orig >> 3);    // bijective, 512 = 8*64
    int bh   = wg >> 4;                          // 16 blocks per (b,h)
    int qc   = wg & 15;
    int q0   = qc * 128 + w * 16;

    const _Float16* qh = qn + (size_t)bh * CSEQ * HEADD;
    const _Float16* kh = kn + (size_t)bh * CSEQ * HEADD;
    const _Float16* vh = vT + (size_t)bh * HEADD * CSEQ;

    half8 aq[2];
    #pragma unroll
    for (int ks = 0; ks < 2; ++ks)
        aq[ks] = *(const half8*)&qh[(size_t)(q0 + l15) * HEADD + ks * 32 + lg * 8];

    f32x4 z = {0.f, 0.f, 0.f, 0.f};
    f32x4 oacc[4];               // O^T: d = db*16 + lg*4 + r, q = l15
    #pragma unroll
    for (int db = 0; db < 4; ++db) oacc[db] = z;
    float mrun = -1e30f, lrun = 0.f;

    int srow_in = lane >> 3;
    int csrc    = (lane & 7) ^ srow_in;

    // 8 waves: each stages one 8-row segment of K and one of V (2 loads/wave)
    auto stage = [&](int buf, int kt) {
        int k0 = kt * KVB;
        int r = w * 8 + srow_in;
        async16(&KsB[buf][w * 512], &kh[(size_t)(k0 + r) * HEADD + csrc * 8]);
        async16(&VsB[buf][w * 512], &vh[(size_t)r * CSEQ + k0 + csrc * 8]);
    };

    stage(0, 0);
    stage(1, 1);
    stage(2, 2);

    for (int kt = 0; kt < NT; ++kt) {
        // wait only for OWN tile's 2 loads; up to 2 prefetched tiles in flight
        if (kt + 2 < NT)      asm volatile("s_waitcnt vmcnt(4)" ::: "memory");
        else if (kt + 1 < NT) asm volatile("s_waitcnt vmcnt(2)" ::: "memory");
        else                  asm volatile("s_waitcnt vmcnt(0)" ::: "memory");
        __builtin_amdgcn_sched_barrier(0);
        __builtin_amdgcn_s_barrier();            // all waves' stage(kt) visible
        __builtin_amdgcn_sched_barrier(0);
        if (kt + 3 < NT) stage((kt + 3) & 3, kt + 3);

        const _Float16* Ks = &KsB[kt & 3][0];
        const _Float16* Vs = &VsB[kt & 3][0];

        // ---- S^T = K * Q^T ----
        f32x4 st[4];
        #pragma unroll
        for (int n = 0; n < 4; ++n) st[n] = z;
        #pragma unroll
        for (int ks = 0; ks < 2; ++ks) {
            half8 ak[4];
            #pragma unroll
            for (int n = 0; n < 4; ++n) {
                int row = n * 16 + l15;
                int ch = (ks * 4 + lg) ^ (row & 7);
                ak[n] = *(const half8*)&Ks[row * 64 + ch * 8];
            }
            #pragma unroll
            for (int n = 0; n < 4; ++n)
                st[n] = __builtin_amdgcn_mfma_f32_16x16x32_f16(ak[n], aq[ks], st[n], 0, 0, 0);
        }

        // ---- online softmax with defer-max; rescale lane-local in O^T ----
        float mx0 = fmaxf(fmaxf(st[0][0], st[0][1]), fmaxf(st[0][2], st[0][3]));
        float mx1 = fmaxf(fmaxf(st[1][0], st[1][1]), fmaxf(st[1][2], st[1][3]));
        float mx2 = fmaxf(fmaxf(st[2][0], st[2][1]), fmaxf(st[2][2], st[2][3]));
        float mx3 = fmaxf(fmaxf(st[3][0], st[3][1]), fmaxf(st[3][2], st[3][3]));
        float tmax = fmaxf(fmaxf(mx0, mx1), fmaxf(mx2, mx3));
        tmax = fmaxf(tmax, __shfl_xor(tmax, 16));
        tmax = fmaxf(tmax, __shfl_xor(tmax, 32));

        if (!__all(tmax <= mrun + 8.f)) {
            float nm = fmaxf(mrun, tmax);
            float sc = __expf(mrun - nm);
            mrun = nm;
            lrun *= sc;
            #pragma unroll
            for (int db = 0; db < 4; ++db) oacc[db] *= sc;   // lane-local (q=l15)
        }

        // ---- P = exp(S - mrun), straight into PV B-fragments ----
        half4v bp[4];
        float ps = 0.f;
        #pragma unroll
        for (int n = 0; n < 4; ++n) {
            float e0 = __expf(st[n][0] - mrun);
            float e1 = __expf(st[n][1] - mrun);
            float e2 = __expf(st[n][2] - mrun);
            float e3 = __expf(st[n][3] - mrun);
            ps += (e0 + e1) + (e2 + e3);
            half4v pk = { (_Float16)e0, (_Float16)e1, (_Float16)e2, (_Float16)e3 };
            bp[n] = pk;
        }
        lrun += ps;   // lane-local partial (k-subset by lg); reduced after loop

        // ---- PV: O^T[d][q] += V^T[d][k] * P^T[k][q], 16x16x16 MFMA ----
        #pragma unroll
        for (int n = 0; n < 4; ++n) {
            #pragma unroll
            for (int db = 0; db < 4; ++db) {
                int row = db * 16 + l15;
                int ch = (n * 2 + (lg >> 1)) ^ (row & 7);
                half4v av = *(const half4v*)&Vs[row * 64 + ch * 8 + (lg & 1) * 4];
                oacc[db] = __builtin_amdgcn_mfma_f32_16x16x16f16(av, bp[n], oacc[db], 0, 0, 0);
            }
        }
        // no trailing barrier: next iteration's top barrier orders buffer reuse
    }

    // ---- lrun cross-lane reduce (once) + O^T store ----
    lrun += __shfl_xor(lrun, 16);
    lrun += __shfl_xor(lrun, 32);
    float inv = 1.f / lrun;
    int b = bh >> 4, h = bh & 15;
    int c = q0 + l15;
    size_t base = ((size_t)b * CSEQ + c) * D_MODEL + h * HEADD;
    #pragma unroll
    for (int db = 0; db < 4; ++db) {
        half4v ov = { (_Float16)(oacc[db][0] * inv), (_Float16)(oacc[db][1] * inv),
                      (_Float16)(oacc[db][2] * inv), (_Float16)(oacc[db][3] * inv) };
        *(half4v*)&o[base + db * 16 + lg * 4] = ov;
    }
}

// ---------------------------------------------------------------------------
extern "C" void kernel_launch(void* const* d_in, const int* in_sizes, int n_in,
                              void* d_out, int out_size, void* d_ws, size_t ws_size,
                              hipStream_t stream)
{
    (void)in_sizes; (void)n_in; (void)out_size; (void)ws_size;
    const float* x      = (const float*)d_in[0];
    const float* ln_q_g = (const float*)d_in[1];
    const float* ln_q_b = (const float*)d_in[2];
    const float* Wq     = (const float*)d_in[3];
    const float* bq     = (const float*)d_in[4];
    const float* ln_kv_g= (const float*)d_in[5];
    const float* ln_kv_b= (const float*)d_in[6];
    const float* Wkv    = (const float*)d_in[7];
    const float* bkv    = (const float*)d_in[8];
    const float* Wout   = (const float*)d_in[9];
    const float* bout   = (const float*)d_in[10];
    const float* lnh_g  = (const float*)d_in[11];
    const float* lnh_b  = (const float*)d_in[12];
    const float* Wr     = (const float*)d_in[13];
    const float* br     = (const float*)d_in[14];
    float* out = (float*)d_out;

    char* ws = (char*)d_ws;
    size_t off = 0;
    auto alloc = [&](size_t bytes) -> void* {
        void* p = ws + off;
        off += (bytes + 255) & ~(size_t)255;
        return p;
    };
    _Float16* WqkvT  = (_Float16*)alloc((size_t)NQKV * D_MODEL * 2);
    _Float16* WoutT  = (_Float16*)alloc((size_t)D_MODEL * D_MODEL * 2);
    float*    bias_e = (float*)   alloc((size_t)NQKV * 4);
    float*    radius = (float*)   alloc((size_t)NROWS * 4);
    float2*   cs_tab = (float2*)  alloc((size_t)CSEQ * NFREQ * 8);
    _Float16* vT     = (_Float16*)alloc((size_t)BATCH * NHEADS * HEADD * CSEQ * 2);
    _Float16* xn     = (_Float16*)alloc((size_t)NROWS * D_MODEL * 2);
    _Float16* qn     = (_Float16*)alloc((size_t)NROWS * D_MODEL * 2);
    _Float16* kn     = (_Float16*)alloc((size_t)NROWS * D_MODEL * 2);
    _Float16* o_h    = (_Float16*)alloc((size_t)NROWS * D_MODEL * 2);

    hipLaunchKernelGGL(prep_misc_kernel, dim3(268), dim3(256), 0, stream,
                       cs_tab, bq, bkv, bias_e);
    hipLaunchKernelGGL(transpose_all_kernel, dim3(4096), dim3(32, 8), 0, stream,
                       Wq, Wkv, Wout, ln_q_g, ln_q_b, ln_kv_g, ln_kv_b,
                       WqkvT, WoutT, bias_e);
    hipLaunchKernelGGL(ln_radius_kernel, dim3(NROWS), dim3(256), 0, stream,
                       x, Wr, br, xn, radius);
    hipLaunchKernelGGL(gemm_qkv_kernel, dim3(768), dim3(256), 0, stream,
                       xn, WqkvT, bias_e, radius, cs_tab, lnh_g, lnh_b, qn, kn, vT);
    hipLaunchKernelGGL(attn_kernel, dim3(BATCH*NHEADS*CSEQ/128), dim3(512), 0, stream,
                       qn, kn, vT, o_h);
    hipLaunchKernelGGL(gemm_out_kernel, dim3(512), dim3(256), 0, stream,
                       o_h, WoutT, bout, out);
}

// Round 19
// 142.635 us; speedup vs baseline: 1.0120x; 1.0120x over previous
//
#include <hip/hip_runtime.h>
#include <math.h>

#define D_MODEL 1024
#define NHEADS  16
#define HEADD   64
#define NFREQ   32
#define BATCH   2
#define CSEQ    2048
#define NROWS   (BATCH*CSEQ)   // 4096
#define NQKV    (3*D_MODEL)    // 3072

typedef _Float16 half8  __attribute__((ext_vector_type(8)));
typedef _Float16 half4v __attribute__((ext_vector_type(4)));
typedef float    f32x4  __attribute__((ext_vector_type(4)));

// async global->LDS, 16B per lane. dest is WAVE-UNIFORM base (HW adds lane*16).
__device__ __forceinline__ void async16(void* lds, const void* g)
{
    __builtin_amdgcn_global_load_lds((const __attribute__((address_space(1))) unsigned int*)g,
                                     (__attribute__((address_space(3))) unsigned int*)lds,
                                     16, 0, 0);
}

// ---------------------------------------------------------------------------
// Fused small prep: blocks 0..255 -> cos/sin table; blocks 256..267 -> bias_eff
// ---------------------------------------------------------------------------
__global__ __launch_bounds__(256) void prep_misc_kernel(
    float2* __restrict__ cs,
    const float* __restrict__ bq, const float* __restrict__ bkv, float* __restrict__ be)
{
    int bid = blockIdx.x;
    int tid = threadIdx.x;
    if (bid < 256) {
        int i = bid * 256 + tid;
        int c = i >> 5, f = i & (NFREQ - 1);
        double mel_max = 2595.0 * log10(21.0);
        double step    = mel_max / (double)(NFREQ - 1);
        double freq    = 200.0 * (pow(10.0, step * (double)f / 2595.0) - 1.0) / 1000.0;
        float fr = (float)freq;
        float th = (float)c * fr;
        float s, co;
        sincosf(th, &s, &co);
        cs[i] = make_float2(co, s);
    } else {
        int i = (bid - 256) * 256 + tid;
        if (i < D_MODEL) be[i] = bq[i];
        else if (i < NQKV) be[i] = bkv[i - D_MODEL];
    }
}

// ---------------------------------------------------------------------------
// All weight transposes in one launch. Transpose + optional LN-gain row-scale
// + cast fp32(R x C)->fp16(C x R); optional LN-bias fold via atomicAdd.
// blocks: [0,1024) Wq ; [1024,3072) Wkv ; [3072,4096) Wout
// ---------------------------------------------------------------------------
__global__ void transpose_all_kernel(
    const float* __restrict__ Wq,  const float* __restrict__ Wkv,
    const float* __restrict__ Wout,
    const float* __restrict__ gq,  const float* __restrict__ bqf,
    const float* __restrict__ gkv, const float* __restrict__ bkvf,
    _Float16* __restrict__ WqkvT, _Float16* __restrict__ WoutT,
    float* __restrict__ bias_acc)
{
    const float* in; _Float16* out; int R, C, rowoff;
    const float* scale; const float* bfold;
    int id = blockIdx.x, bx, by;
    if (id < 1024) {
        in = Wq; out = WqkvT; R = D_MODEL; C = D_MODEL; rowoff = 0;
        scale = gq; bfold = bqf;
        bx = (id & 31) * 32; by = (id >> 5) * 32;
    } else if (id < 3072) {
        int t = id - 1024;
        in = Wkv; out = WqkvT; R = D_MODEL; C = 2 * D_MODEL; rowoff = D_MODEL;
        scale = gkv; bfold = bkvf;
        bx = (t & 63) * 32; by = (t >> 6) * 32;
    } else {
        int t = id - 3072;
        in = Wout; out = WoutT; R = D_MODEL; C = D_MODEL; rowoff = 0;
        scale = nullptr; bfold = nullptr;
        bx = (t & 31) * 32; by = (t >> 5) * 32;
    }

    __shared__ float tb[32][33];
    __shared__ float part[4][32];
    int tx = threadIdx.x, ty = threadIdx.y;
    #pragma unroll
    for (int i = ty; i < 32; i += 8)
        tb[i][tx] = in[(size_t)(by + i) * C + bx + tx];
    __syncthreads();
    float sc = scale ? scale[by + tx] : 1.f;
    #pragma unroll
    for (int i = ty; i < 32; i += 8)
        out[(size_t)(rowoff + bx + i) * R + by + tx] = (_Float16)(tb[tx][i] * sc);
    if (bfold) {
        float p = 0.f;
        #pragma unroll
        for (int i = ty; i < 32; i += 8)
            p += bfold[by + i] * tb[i][tx];
        p += __shfl_xor(p, 32);
        if ((ty & 1) == 0) part[ty >> 1][tx] = p;
        __syncthreads();
        if (ty == 0)
            atomicAdd(&bias_acc[rowoff + bx + tx],
                      part[0][tx] + part[1][tx] + part[2][tx] + part[3][tx]);
    }
}

// ---------------------------------------------------------------------------
// LN stats + radius; writes xn fp16 (normalized; gains folded into weights)
// ---------------------------------------------------------------------------
__global__ __launch_bounds__(256) void ln_radius_kernel(
    const float* __restrict__ x,
    const float* __restrict__ Wr,  const float* __restrict__ br,
    _Float16* __restrict__ xn, float* __restrict__ radius)
{
    int row = blockIdx.x;
    int tid = threadIdx.x;
    float4 xv = ((const float4*)(x + (size_t)row * D_MODEL))[tid];
    float4 wv = ((const float4*)Wr)[tid];
    float s  = xv.x + xv.y + xv.z + xv.w;
    float ss = xv.x*xv.x + xv.y*xv.y + xv.z*xv.z + xv.w*xv.w;
    float dr = xv.x*wv.x + xv.y*wv.y + xv.z*wv.z + xv.w*wv.w;
    #pragma unroll
    for (int off = 1; off < 64; off <<= 1) {
        s  += __shfl_xor(s, off);
        ss += __shfl_xor(ss, off);
        dr += __shfl_xor(dr, off);
    }
    __shared__ float red[3][4];
    int w = tid >> 6, lane = tid & 63;
    if (lane == 0) { red[0][w] = s; red[1][w] = ss; red[2][w] = dr; }
    __syncthreads();
    s  = red[0][0] + red[0][1] + red[0][2] + red[0][3];
    ss = red[1][0] + red[1][1] + red[1][2] + red[1][3];
    float mean = s * (1.f / D_MODEL);
    float var  = ss * (1.f / D_MODEL) - mean * mean;
    float rinv = rsqrtf(var + 1e-5f);
    half4v o4 = { (_Float16)((xv.x - mean) * rinv), (_Float16)((xv.y - mean) * rinv),
                  (_Float16)((xv.z - mean) * rinv), (_Float16)((xv.w - mean) * rinv) };
    *(half4v*)&xn[(size_t)row * D_MODEL + tid * 4] = o4;
    if (tid == 0) {
        float drt = red[2][0] + red[2][1] + red[2][2] + red[2][3];
        float p = (drt + br[0]) * 0.01f;
        radius[row] = fminf(fmaxf(p, 0.5f), 2.0f);
    }
}

// ---------------------------------------------------------------------------
// Pipelined GEMM core (128x128): BK=32, THREE LDS buffers, counted
// s_waitcnt vmcnt(4) + raw s_barrier; stage(t+1) loads stay in flight.
// ---------------------------------------------------------------------------
__device__ __forceinline__ void gemm_core32p(
    const _Float16* __restrict__ A, const _Float16* __restrict__ B,
    int bm, int bn, int K, _Float16* As, _Float16* Bs, f32x4 (*acc)[4])
{
    int tid = threadIdx.x, lane = tid & 63, w = tid >> 6;
    int wm = w >> 1, wn = w & 1;
    int l15 = lane & 15, lg = lane >> 4;
    int sr  = lane >> 2;
    int sch = lane & 3;

    auto stage = [&](int buf, int k0) {
        #pragma unroll
        for (int i = 0; i < 2; ++i) {
            int seg = w * 2 + i;
            int row = seg * 16 + sr;
            async16(&As[buf * 4096 + seg * 512], &A[(size_t)(bm + row) * K + k0 + sch * 8]);
            async16(&Bs[buf * 4096 + seg * 512], &B[(size_t)(bn + row) * K + k0 + sch * 8]);
        }
    };

    int nt = K >> 5;
    stage(0, 0);
    stage(1, 32);

    for (int t = 0; t < nt; ++t) {
        if (t + 1 < nt) asm volatile("s_waitcnt vmcnt(4)" ::: "memory");
        else            asm volatile("s_waitcnt vmcnt(0)" ::: "memory");
        __builtin_amdgcn_sched_barrier(0);
        __builtin_amdgcn_s_barrier();
        __builtin_amdgcn_sched_barrier(0);
        if (t + 2 < nt) stage((t + 2) % 3, (t + 2) << 5);

        const _Float16* Ab = &As[(t % 3) * 4096];
        const _Float16* Bb = &Bs[(t % 3) * 4096];
        half8 af[4], bf[4];
        #pragma unroll
        for (int m = 0; m < 4; ++m)
            af[m] = *(const half8*)&Ab[(wm * 64 + m * 16 + l15) * 32 + lg * 8];
        #pragma unroll
        for (int n = 0; n < 4; ++n)
            bf[n] = *(const half8*)&Bb[(wn * 64 + n * 16 + l15) * 32 + lg * 8];
        #pragma unroll
        for (int m = 0; m < 4; ++m)
            #pragma unroll
            for (int n = 0; n < 4; ++n)
                acc[m][n] = __builtin_amdgcn_mfma_f32_16x16x32_f16(af[m], bf[n], acc[m][n], 0, 0, 0);
    }
}

// ---------------------------------------------------------------------------
// Fused qkv GEMM: xn (M=4096 x K=1024) x WqkvT (N=3072) + bias_eff.
// q/k epilogue: bias + RoPE + head-LN (q pre-scaled 0.125 = 1/sqrt(HD)).
// V epilogue: bias + DIRECT transposed store into vT (B,H,HD,C).
// ---------------------------------------------------------------------------
__global__ __launch_bounds__(256, 3) void gemm_qkv_kernel(
    const _Float16* __restrict__ xn,  const _Float16* __restrict__ WT,
    const float* __restrict__ bias_eff,
    const float* __restrict__ radius, const float2* __restrict__ cs_tab,
    const float* __restrict__ lnh_g,  const float* __restrict__ lnh_b,
    _Float16* __restrict__ qn, _Float16* __restrict__ kn, _Float16* __restrict__ vT)
{
    __shared__ _Float16 As[3 * 4096];
    __shared__ _Float16 Bs[3 * 4096];
    int orig = blockIdx.x;
    int wg = (orig & 7) * 96 + (orig >> 3);   // bijective, 768 = 8*96
    int bm = (wg / 24) * 128;
    int bn = (wg % 24) * 128;

    f32x4 acc[4][4];
    f32x4 z = {0.f, 0.f, 0.f, 0.f};
    #pragma unroll
    for (int m = 0; m < 4; ++m)
        #pragma unroll
        for (int n = 0; n < 4; ++n) acc[m][n] = z;

    gemm_core32p(xn, WT, bm, bn, D_MODEL, As, Bs, acc);

    int tid = threadIdx.x, lane = tid & 63, w = tid >> 6;
    int wm = w >> 1, wn = w & 1;
    int l15 = lane & 15, lg = lane >> 4;
    int colbase = bn + wn * 64;

    float bb4[4];
    #pragma unroll
    for (int n = 0; n < 4; ++n) bb4[n] = bias_eff[colbase + n * 16 + l15];

    if (colbase >= 2 * D_MODEL) {
        // ---- V epilogue: bias + direct transposed store to vT (B,H,HD,C) ----
        int vcolb = colbase - 2 * D_MODEL;
        int h = vcolb >> 6;
        #pragma unroll
        for (int m = 0; m < 4; ++m) {
            int row0 = bm + wm * 64 + m * 16 + lg * 4;
            int b = row0 >> 11, c = row0 & (CSEQ - 1);
            #pragma unroll
            for (int n = 0; n < 4; ++n) {
                int d = n * 16 + l15;
                half4v v4 = { (_Float16)(acc[m][n][0] + bb4[n]),
                              (_Float16)(acc[m][n][1] + bb4[n]),
                              (_Float16)(acc[m][n][2] + bb4[n]),
                              (_Float16)(acc[m][n][3] + bb4[n]) };
                *(half4v*)&vT[((size_t)(b * NHEADS + h) * HEADD + d) * CSEQ + c] = v4;
            }
        }
        return;
    }

    bool isq = colbase < D_MODEL;
    int h = (colbase & (D_MODEL - 1)) >> 6;
    _Float16* dst = isq ? qn : kn;
    float qs = isq ? 0.125f : 1.f;
    bool im = (l15 & 1) != 0;

    float g4[4], bh4[4];
    #pragma unroll
    for (int n = 0; n < 4; ++n) {
        g4[n]  = lnh_g[n * 16 + l15];
        bh4[n] = lnh_b[n * 16 + l15];
    }

    #pragma unroll
    for (int m = 0; m < 4; ++m)
        #pragma unroll
        for (int r = 0; r < 4; ++r) {
            int row = bm + wm * 64 + m * 16 + lg * 4 + r;
            int b = row >> 11, c = row & (CSEQ - 1);
            float rr = radius[row];
            float vals[4];
            float s = 0.f, ss = 0.f;
            #pragma unroll
            for (int n = 0; n < 4; ++n) {
                float v0 = acc[m][n][r] + bb4[n];
                float pr = __shfl_xor(v0, 1);
                float2 cs = cs_tab[c * NFREQ + ((n * 16 + l15) >> 1)];
                float xr_ = im ? pr : v0;
                float xi_ = im ? v0 : pr;
                float rot = im ? rr * (xr_ * cs.y + xi_ * cs.x)
                               : rr * (xr_ * cs.x - xi_ * cs.y);
                vals[n] = rot;
                s += rot; ss += rot * rot;
            }
            #pragma unroll
            for (int off = 1; off < 16; off <<= 1) {
                s  += __shfl_xor(s, off);
                ss += __shfl_xor(ss, off);
            }
            float mean = s * (1.f / 64.f);
            float var  = ss * (1.f / 64.f) - mean * mean;
            float ri   = rsqrtf(var + 1e-5f);
            size_t base = ((size_t)(b * NHEADS + h) * CSEQ + c) * HEADD;
            #pragma unroll
            for (int n = 0; n < 4; ++n) {
                float o = ((vals[n] - mean) * ri * g4[n] + bh4[n]) * qs;
                dst[base + n * 16 + l15] = (_Float16)o;
            }
        }
}

// ---------------------------------------------------------------------------
// Output GEMM: 128x64 tiles, grid 512 (2 blocks/CU), 3-buffer counted-vmcnt
// pipeline (3 loads/stage -> vmcnt(3)).
// ---------------------------------------------------------------------------
__global__ __launch_bounds__(256, 4) void gemm_out_kernel(
    const _Float16* __restrict__ A, const _Float16* __restrict__ BT,
    const float* __restrict__ bias, float* __restrict__ C)
{
    __shared__ _Float16 As[3 * 4096];
    __shared__ _Float16 Bs[3 * 2048];
    int orig = blockIdx.x;
    int wg = (orig & 7) * 64 + (orig >> 3);   // bijective, 512 = 8*64
    int bm = (wg >> 4) * 128;                 // 32 m-tiles
    int bn = (wg & 15) * 64;                  // 16 n-tiles

    int tid = threadIdx.x, lane = tid & 63, w = tid >> 6;
    int wm = w >> 1, wn = w & 1;
    int l15 = lane & 15, lg = lane >> 4;
    int sr  = lane >> 2;
    int sch = lane & 3;

    f32x4 acc[4][2];
    f32x4 z = {0.f, 0.f, 0.f, 0.f};
    #pragma unroll
    for (int m = 0; m < 4; ++m)
        #pragma unroll
        for (int n = 0; n < 2; ++n) acc[m][n] = z;

    auto stage = [&](int buf, int k0) {
        #pragma unroll
        for (int i = 0; i < 2; ++i) {
            int seg = w * 2 + i;
            int row = seg * 16 + sr;
            async16(&As[buf * 4096 + seg * 512], &A[(size_t)(bm + row) * D_MODEL + k0 + sch * 8]);
        }
        int brow = w * 16 + sr;
        async16(&Bs[buf * 2048 + w * 512], &BT[(size_t)(bn + brow) * D_MODEL + k0 + sch * 8]);
    };

    stage(0, 0);
    stage(1, 32);
    for (int t = 0; t < 32; ++t) {
        if (t + 1 < 32) asm volatile("s_waitcnt vmcnt(3)" ::: "memory");
        else            asm volatile("s_waitcnt vmcnt(0)" ::: "memory");
        __builtin_amdgcn_sched_barrier(0);
        __builtin_amdgcn_s_barrier();
        __builtin_amdgcn_sched_barrier(0);
        if (t + 2 < 32) stage((t + 2) % 3, (t + 2) << 5);

        const _Float16* Ab = &As[(t % 3) * 4096];
        const _Float16* Bb = &Bs[(t % 3) * 2048];
        half8 af[4], bf[2];
        #pragma unroll
        for (int m = 0; m < 4; ++m)
            af[m] = *(const half8*)&Ab[(wm * 64 + m * 16 + l15) * 32 + lg * 8];
        #pragma unroll
        for (int n = 0; n < 2; ++n)
            bf[n] = *(const half8*)&Bb[(wn * 32 + n * 16 + l15) * 32 + lg * 8];
        #pragma unroll
        for (int m = 0; m < 4; ++m)
            #pragma unroll
            for (int n = 0; n < 2; ++n)
                acc[m][n] = __builtin_amdgcn_mfma_f32_16x16x32_f16(af[m], bf[n], acc[m][n], 0, 0, 0);
    }

    #pragma unroll
    for (int m = 0; m < 4; ++m) {
        int row = bm + wm * 64 + m * 16 + lg * 4;
        #pragma unroll
        for (int n = 0; n < 2; ++n) {
            int col = bn + wn * 32 + n * 16 + l15;
            float bb = bias[col];
            #pragma unroll
            for (int r = 0; r < 4; ++r)
                C[(size_t)(row + r) * D_MODEL + col] = acc[m][n][r] + bb;
        }
    }
}

// ---------------------------------------------------------------------------
// Flash attention (final, R17-measured-best): 8 waves x 16 q = 128 q/block,
// 512 threads, grid 512, reg-P O^T PV via mfma_f32_16x16x16f16, online
// defer-max softmax, THREE-buffer staging with counted s_waitcnt vmcnt(2) +
// raw s_barrier: stage(kt+1)'s loads stay in flight across the barrier.
// LDS 48KB, 2 blocks/CU x 8 waves = 16 waves/CU.
// ---------------------------------------------------------------------------
#define KVB 64
#define NT  (CSEQ / KVB)

__global__ __launch_bounds__(512, 4) void attn_kernel(
    const _Float16* __restrict__ qn, const _Float16* __restrict__ kn,
    const _Float16* __restrict__ vT, _Float16* __restrict__ o)
{
    __shared__ _Float16 KsB[3][KVB * 64];   // 24 KB
    __shared__ _Float16 VsB[3][KVB * 64];   // 24 KB
    int tid = threadIdx.x, lane = tid & 63, w = tid >> 6;   // w = 0..7
    int l15 = lane & 15, lg = lane >> 4;

    int orig = blockIdx.x;
    int wg   = (orig & 7) * 64 + (orig >> 3);    // bijective, 512 = 8*64
    int bh   = wg >> 4;                          // 16 blocks per (b,h)
    int qc   = wg & 15;
    int q0   = qc * 128 + w * 16;

    const _Float16* qh = qn + (size_t)bh * CSEQ * HEADD;
    const _Float16* kh = kn + (size_t)bh * CSEQ * HEADD;
    const _Float16* vh = vT + (size_t)bh * HEADD * CSEQ;

    half8 aq[2];
    #pragma unroll
    for (int ks = 0; ks < 2; ++ks)
        aq[ks] = *(const half8*)&qh[(size_t)(q0 + l15) * HEADD + ks * 32 + lg * 8];

    f32x4 z = {0.f, 0.f, 0.f, 0.f};
    f32x4 oacc[4];               // O^T: d = db*16 + lg*4 + r, q = l15
    #pragma unroll
    for (int db = 0; db < 4; ++db) oacc[db] = z;
    float mrun = -1e30f, lrun = 0.f;

    int srow_in = lane >> 3;
    int csrc    = (lane & 7) ^ srow_in;

    // 8 waves: each stages one 8-row segment of K and one of V (2 loads/wave)
    auto stage = [&](int buf, int kt) {
        int k0 = kt * KVB;
        int r = w * 8 + srow_in;
        async16(&KsB[buf][w * 512], &kh[(size_t)(k0 + r) * HEADD + csrc * 8]);
        async16(&VsB[buf][w * 512], &vh[(size_t)r * CSEQ + k0 + csrc * 8]);
    };

    stage(0, 0);
    stage(1, 1);

    for (int kt = 0; kt < NT; ++kt) {
        // wait only for OWN tile's staging loads (next tile's 2 stay in flight)
        if (kt + 1 < NT) asm volatile("s_waitcnt vmcnt(2)" ::: "memory");
        else             asm volatile("s_waitcnt vmcnt(0)" ::: "memory");
        __builtin_amdgcn_sched_barrier(0);
        __builtin_amdgcn_s_barrier();            // all waves' stage(kt) visible
        __builtin_amdgcn_sched_barrier(0);
        if (kt + 2 < NT) stage((kt + 2) % 3, kt + 2);

        const _Float16* Ks = &KsB[kt % 3][0];
        const _Float16* Vs = &VsB[kt % 3][0];

        // ---- S^T = K * Q^T ----
        f32x4 st[4];
        #pragma unroll
        for (int n = 0; n < 4; ++n) st[n] = z;
        #pragma unroll
        for (int ks = 0; ks < 2; ++ks) {
            half8 ak[4];
            #pragma unroll
            for (int n = 0; n < 4; ++n) {
                int row = n * 16 + l15;
                int ch = (ks * 4 + lg) ^ (row & 7);
                ak[n] = *(const half8*)&Ks[row * 64 + ch * 8];
            }
            #pragma unroll
            for (int n = 0; n < 4; ++n)
                st[n] = __builtin_amdgcn_mfma_f32_16x16x32_f16(ak[n], aq[ks], st[n], 0, 0, 0);
        }

        // ---- online softmax with defer-max; rescale lane-local in O^T ----
        float mx0 = fmaxf(fmaxf(st[0][0], st[0][1]), fmaxf(st[0][2], st[0][3]));
        float mx1 = fmaxf(fmaxf(st[1][0], st[1][1]), fmaxf(st[1][2], st[1][3]));
        float mx2 = fmaxf(fmaxf(st[2][0], st[2][1]), fmaxf(st[2][2], st[2][3]));
        float mx3 = fmaxf(fmaxf(st[3][0], st[3][1]), fmaxf(st[3][2], st[3][3]));
        float tmax = fmaxf(fmaxf(mx0, mx1), fmaxf(mx2, mx3));
        tmax = fmaxf(tmax, __shfl_xor(tmax, 16));
        tmax = fmaxf(tmax, __shfl_xor(tmax, 32));

        if (!__all(tmax <= mrun + 8.f)) {
            float nm = fmaxf(mrun, tmax);
            float sc = __expf(mrun - nm);
            mrun = nm;
            lrun *= sc;
            #pragma unroll
            for (int db = 0; db < 4; ++db) oacc[db] *= sc;   // lane-local (q=l15)
        }

        // ---- P = exp(S - mrun), straight into PV B-fragments ----
        half4v bp[4];
        float ps = 0.f;
        #pragma unroll
        for (int n = 0; n < 4; ++n) {
            float e0 = __expf(st[n][0] - mrun);
            float e1 = __expf(st[n][1] - mrun);
            float e2 = __expf(st[n][2] - mrun);
            float e3 = __expf(st[n][3] - mrun);
            ps += (e0 + e1) + (e2 + e3);
            half4v pk = { (_Float16)e0, (_Float16)e1, (_Float16)e2, (_Float16)e3 };
            bp[n] = pk;
        }
        lrun += ps;   // lane-local partial (k-subset by lg); reduced after loop

        // ---- PV: O^T[d][q] += V^T[d][k] * P^T[k][q], 16x16x16 MFMA ----
        #pragma unroll
        for (int n = 0; n < 4; ++n) {
            #pragma unroll
            for (int db = 0; db < 4; ++db) {
                int row = db * 16 + l15;
                int ch = (n * 2 + (lg >> 1)) ^ (row & 7);
                half4v av = *(const half4v*)&Vs[row * 64 + ch * 8 + (lg & 1) * 4];
                oacc[db] = __builtin_amdgcn_mfma_f32_16x16x16f16(av, bp[n], oacc[db], 0, 0, 0);
            }
        }
        // no trailing barrier: next iteration's top barrier orders reuse
    }

    // ---- lrun cross-lane reduce (once) + O^T store ----
    lrun += __shfl_xor(lrun, 16);
    lrun += __shfl_xor(lrun, 32);
    float inv = 1.f / lrun;
    int b = bh >> 4, h = bh & 15;
    int c = q0 + l15;
    size_t base = ((size_t)b * CSEQ + c) * D_MODEL + h * HEADD;
    #pragma unroll
    for (int db = 0; db < 4; ++db) {
        half4v ov = { (_Float16)(oacc[db][0] * inv), (_Float16)(oacc[db][1] * inv),
                      (_Float16)(oacc[db][2] * inv), (_Float16)(oacc[db][3] * inv) };
        *(half4v*)&o[base + db * 16 + lg * 4] = ov;
    }
}

// ---------------------------------------------------------------------------
extern "C" void kernel_launch(void* const* d_in, const int* in_sizes, int n_in,
                              void* d_out, int out_size, void* d_ws, size_t ws_size,
                              hipStream_t stream)
{
    (void)in_sizes; (void)n_in; (void)out_size; (void)ws_size;
    const float* x      = (const float*)d_in[0];
    const float* ln_q_g = (const float*)d_in[1];
    const float* ln_q_b = (const float*)d_in[2];
    const float* Wq     = (const float*)d_in[3];
    const float* bq     = (const float*)d_in[4];
    const float* ln_kv_g= (const float*)d_in[5];
    const float* ln_kv_b= (const float*)d_in[6];
    const float* Wkv    = (const float*)d_in[7];
    const float* bkv    = (const float*)d_in[8];
    const float* Wout   = (const float*)d_in[9];
    const float* bout   = (const float*)d_in[10];
    const float* lnh_g  = (const float*)d_in[11];
    const float* lnh_b  = (const float*)d_in[12];
    const float* Wr     = (const float*)d_in[13];
    const float* br     = (const float*)d_in[14];
    float* out = (float*)d_out;

    char* ws = (char*)d_ws;
    size_t off = 0;
    auto alloc = [&](size_t bytes) -> void* {
        void* p = ws + off;
        off += (bytes + 255) & ~(size_t)255;
        return p;
    };
    _Float16* WqkvT  = (_Float16*)alloc((size_t)NQKV * D_MODEL * 2);
    _Float16* WoutT  = (_Float16*)alloc((size_t)D_MODEL * D_MODEL * 2);
    float*    bias_e = (float*)   alloc((size_t)NQKV * 4);
    float*    radius = (float*)   alloc((size_t)NROWS * 4);
    float2*   cs_tab = (float2*)  alloc((size_t)CSEQ * NFREQ * 8);
    _Float16* vT     = (_Float16*)alloc((size_t)BATCH * NHEADS * HEADD * CSEQ * 2);
    _Float16* xn     = (_Float16*)alloc((size_t)NROWS * D_MODEL * 2);
    _Float16* qn     = (_Float16*)alloc((size_t)NROWS * D_MODEL * 2);
    _Float16* kn     = (_Float16*)alloc((size_t)NROWS * D_MODEL * 2);
    _Float16* o_h    = (_Float16*)alloc((size_t)NROWS * D_MODEL * 2);

    hipLaunchKernelGGL(prep_misc_kernel, dim3(268), dim3(256), 0, stream,
                       cs_tab, bq, bkv, bias_e);
    hipLaunchKernelGGL(transpose_all_kernel, dim3(4096), dim3(32, 8), 0, stream,
                       Wq, Wkv, Wout, ln_q_g, ln_q_b, ln_kv_g, ln_kv_b,
                       WqkvT, WoutT, bias_e);
    hipLaunchKernelGGL(ln_radius_kernel, dim3(NROWS), dim3(256), 0, stream,
                       x, Wr, br, xn, radius);
    hipLaunchKernelGGL(gemm_qkv_kernel, dim3(768), dim3(256), 0, stream,
                       xn, WqkvT, bias_e, radius, cs_tab, lnh_g, lnh_b, qn, kn, vT);
    hipLaunchKernelGGL(attn_kernel, dim3(BATCH*NHEADS*CSEQ/128), dim3(512), 0, stream,
                       qn, kn, vT, o_h);
    hipLaunchKernelGGL(gemm_out_kernel, dim3(512), dim3(256), 0, stream,
                       o_h, WoutT, bout, out);
}